// Round 4
// baseline (275.115 us; speedup 1.0000x reference)
//
#include <hip/hip_runtime.h>
#include <hip/hip_bf16.h>

typedef short bf16x8 __attribute__((ext_vector_type(8)));
typedef float f32x4 __attribute__((ext_vector_type(4)));
typedef _Float16 f16x2 __attribute__((ext_vector_type(2)));
typedef _Float16 f16x8v __attribute__((ext_vector_type(8)));
typedef unsigned short u16x8 __attribute__((ext_vector_type(8)));

static __device__ __forceinline__ unsigned short f2bf_rne(float f) {
    unsigned int u = __float_as_uint(f);
    u += 0x7fff + ((u >> 16) & 1);
    return (unsigned short)(u >> 16);
}
static __device__ __forceinline__ float bf2f(unsigned short h) {
    return __uint_as_float(((unsigned int)h) << 16);
}

// split one fp32 weight element into hi/lo bf16 at its fragment-ordered slot
// B-frag layout for mfma_f32_16x16x32_bf16: lane=quad*16+(n&15) holds k=kc*32+quad*8+j
static __device__ __forceinline__ void wsplit_one(const float* W, unsigned short* hi,
                                                  unsigned short* lo, int BN, int idx) {
    int k = idx / BN, n = idx % BN;
    float w = W[idx];
    unsigned short h = f2bf_rne(w);
    unsigned short l = f2bf_rne(w - bf2f(h));
    int CT = BN >> 4;
    int kc = k >> 5, quad = (k >> 3) & 3, j = k & 7;
    int ct = n >> 4, c = n & 15;
    int slot = (((kc * CT + ct) * 4 + quad) * 16 + c) * 8 + j;
    hi[slot] = h;
    lo[slot] = l;
}

// ===================== GEMM bodies (BM=64; 782 blocks balance across 256 CUs) ==========
// Layers 2/3 read A as PRE-SPLIT bf16 hi/lo planes written by the agg epilogue (R14 win).

// layer-1 variant: A is external fp32 x, split during staging
template<int BN>
static __device__ __forceinline__ void gemm_body_f32(const float* __restrict__ A,
                        const unsigned short* __restrict__ Whi, const unsigned short* __restrict__ Wlo,
                        _Float16* __restrict__ C, int N, int blk,
                        unsigned short* AhiS, unsigned short* AloS) {
    constexpr int CT = BN / 16;
    const int tid = threadIdx.x;
    const int wave = tid >> 6;
    const int lane = tid & 63;
    const int quad = lane >> 4;
    const int c16 = lane & 15;
    const int row0 = blk * 64;

    f32x4 acc[CT];
    #pragma unroll
    for (int t = 0; t < CT; ++t) acc[t] = (f32x4){0.f, 0.f, 0.f, 0.f};

    for (int kc = 0; kc < 4; ++kc) {
        #pragma unroll
        for (int r = 0; r < 2; ++r) {
            int f4 = tid + r * 256;
            int arow = f4 >> 3;
            int c4 = f4 & 7;
            int grow = row0 + arow;
            float4 v = make_float4(0.f, 0.f, 0.f, 0.f);
            if (grow < N) v = *(const float4*)&A[(size_t)grow * 128 + kc * 32 + c4 * 4];
            unsigned short h0 = f2bf_rne(v.x), h1 = f2bf_rne(v.y), h2 = f2bf_rne(v.z), h3 = f2bf_rne(v.w);
            ushort4 hv = make_ushort4(h0, h1, h2, h3);
            ushort4 lv = make_ushort4(f2bf_rne(v.x - bf2f(h0)), f2bf_rne(v.y - bf2f(h1)),
                                      f2bf_rne(v.z - bf2f(h2)), f2bf_rne(v.w - bf2f(h3)));
            int q = c4 >> 1;
            int joff = (c4 & 1) * 4;
            int base = (q * 64 + arow) * 8 + joff;
            *(ushort4*)&AhiS[base] = hv;
            *(ushort4*)&AloS[base] = lv;
        }
        __syncthreads();

        int abase = (quad * 64 + wave * 16 + c16) * 8;
        bf16x8 ahi = *(const bf16x8*)&AhiS[abase];
        bf16x8 alo = *(const bf16x8*)&AloS[abase];

        #pragma unroll
        for (int ct = 0; ct < CT; ++ct) {
            size_t bslot = ((size_t)(kc * CT + ct) * 64 + lane) * 8;
            bf16x8 bhi = *(const bf16x8*)&Whi[bslot];
            bf16x8 blo = *(const bf16x8*)&Wlo[bslot];
            acc[ct] = __builtin_amdgcn_mfma_f32_16x16x32_bf16(ahi, bhi, acc[ct], 0, 0, 0);
            acc[ct] = __builtin_amdgcn_mfma_f32_16x16x32_bf16(ahi, blo, acc[ct], 0, 0, 0);
            acc[ct] = __builtin_amdgcn_mfma_f32_16x16x32_bf16(alo, bhi, acc[ct], 0, 0, 0);
        }
        __syncthreads();
    }

    #pragma unroll
    for (int ct = 0; ct < CT; ++ct) {
        #pragma unroll
        for (int r = 0; r < 4; ++r) {
            int grow = row0 + wave * 16 + quad * 4 + r;
            if (grow < N) C[(size_t)grow * BN + ct * 16 + c16] = (_Float16)acc[ct][r];
        }
    }
}

// layers-2/3 variant: A given as bf16 hi/lo planes [node][128]; staging is a pure copy.
template<int BN>
static __device__ __forceinline__ void gemm_body_bf(const unsigned short* __restrict__ Ahi,
                        const unsigned short* __restrict__ Alo,
                        const unsigned short* __restrict__ Whi, const unsigned short* __restrict__ Wlo,
                        _Float16* __restrict__ C, int N, int blk,
                        unsigned short* AhiS, unsigned short* AloS) {
    constexpr int CT = BN / 16;
    const int tid = threadIdx.x;
    const int wave = tid >> 6;
    const int lane = tid & 63;
    const int quad = lane >> 4;
    const int c16 = lane & 15;
    const int row0 = blk * 64;
    const int arow = tid >> 2;
    const int cblk = tid & 3;
    const int grow = row0 + arow;
    const bool inb = grow < N;
    const size_t agbase = (size_t)grow * 128 + cblk * 8;
    const int sbase = (cblk * 64 + arow) * 8;

    f32x4 acc[CT];
    #pragma unroll
    for (int t = 0; t < CT; ++t) acc[t] = (f32x4){0.f, 0.f, 0.f, 0.f};

    for (int kc = 0; kc < 4; ++kc) {
        u16x8 hv = {0, 0, 0, 0, 0, 0, 0, 0};
        u16x8 lv = {0, 0, 0, 0, 0, 0, 0, 0};
        if (inb) {
            hv = *(const u16x8*)&Ahi[agbase + kc * 32];
            lv = *(const u16x8*)&Alo[agbase + kc * 32];
        }
        *(u16x8*)&AhiS[sbase] = hv;
        *(u16x8*)&AloS[sbase] = lv;
        __syncthreads();

        int abase = (quad * 64 + wave * 16 + c16) * 8;
        bf16x8 ahi = *(const bf16x8*)&AhiS[abase];
        bf16x8 alo = *(const bf16x8*)&AloS[abase];

        #pragma unroll
        for (int ct = 0; ct < CT; ++ct) {
            size_t bslot = ((size_t)(kc * CT + ct) * 64 + lane) * 8;
            bf16x8 bhi = *(const bf16x8*)&Whi[bslot];
            bf16x8 blo = *(const bf16x8*)&Wlo[bslot];
            acc[ct] = __builtin_amdgcn_mfma_f32_16x16x32_bf16(ahi, bhi, acc[ct], 0, 0, 0);
            acc[ct] = __builtin_amdgcn_mfma_f32_16x16x32_bf16(ahi, blo, acc[ct], 0, 0, 0);
            acc[ct] = __builtin_amdgcn_mfma_f32_16x16x32_bf16(alo, bhi, acc[ct], 0, 0, 0);
        }
        __syncthreads();
    }

    #pragma unroll
    for (int ct = 0; ct < CT; ++ct) {
        #pragma unroll
        for (int r = 0; r < 4; ++r) {
            int gr = row0 + wave * 16 + quad * 4 + r;
            if (gr < N) C[(size_t)gr * BN + ct * 16 + c16] = (_Float16)acc[ct][r];
        }
    }
}

// ===================== preprocessing =====================

__global__ __launch_bounds__(256) void k_count_wsplit(const int* __restrict__ dst, int* __restrict__ deg,
                          int* __restrict__ rank,
                          const float* __restrict__ W1, const float* __restrict__ W2, const float* __restrict__ W3,
                          unsigned short* __restrict__ W1hi, unsigned short* __restrict__ W1lo,
                          unsigned short* __restrict__ W2hi, unsigned short* __restrict__ W2lo,
                          unsigned short* __restrict__ W3hi, unsigned short* __restrict__ W3lo,
                          int E) {
    int e = blockIdx.x * blockDim.x + threadIdx.x;
    if (e < E) rank[e] = atomicAdd(&deg[dst[e]], 1);
    if (e < 128 * 128) {
        wsplit_one(W1, W1hi, W1lo, 128, e);
        wsplit_one(W2, W2hi, W2lo, 128, e);
    }
    if (e < 128 * 64) wsplit_one(W3, W3hi, W3lo, 64, e);
}

__global__ __launch_bounds__(1024) void k_scan(const int* __restrict__ deg, float* __restrict__ dinv,
                                               int* __restrict__ row_start, int N) {
    __shared__ int s[1024];
    __shared__ int wsum[16];
    __shared__ int prefix;
    const int t = threadIdx.x;
    const int base = blockIdx.x * 1024;

    {
        int v = 0;
        for (int j = t; j < base; j += 1024) v += deg[j];
        for (int off = 32; off > 0; off >>= 1) v += __shfl_down(v, off, 64);
        if ((t & 63) == 0) wsum[t >> 6] = v;
        __syncthreads();
        if (t == 0) {
            int acc = 0;
            #pragma unroll
            for (int k = 0; k < 16; ++k) acc += wsum[k];
            prefix = acc;
        }
    }

    int i = base + t;
    int v = 0;
    if (i < N) {
        v = deg[i];
        dinv[i] = rsqrtf((float)v + 1.0f);
    }
    s[t] = v;
    __syncthreads();
    for (int off = 1; off < 1024; off <<= 1) {
        int x = (t >= off) ? s[t - off] : 0;
        __syncthreads();
        s[t] += x;
        __syncthreads();
    }
    if (i <= N) row_start[i] = prefix + s[t] - v;   // row_start[N] = E via deg-past-N = 0
}

// ===================== fused: layer-1 GEMM + CSR scatter (independent work) =====================

__global__ __launch_bounds__(256, 2) void k_gemm1_scatter(const float* __restrict__ A,
                          const unsigned short* __restrict__ Whi, const unsigned short* __restrict__ Wlo,
                          _Float16* __restrict__ C, int N, int gemmGrid,
                          const int* __restrict__ src, const int* __restrict__ dst,
                          const int* __restrict__ row_start, const int* __restrict__ rank,
                          const float* __restrict__ dinv, int2* __restrict__ cv, int E) {
    __shared__ unsigned short AhiS[4 * 64 * 8];
    __shared__ unsigned short AloS[4 * 64 * 8];
    if ((int)blockIdx.x < gemmGrid) {
        gemm_body_f32<128>(A, Whi, Wlo, C, N, blockIdx.x, AhiS, AloS);
    } else {
        int e = (blockIdx.x - gemmGrid) * 256 + threadIdx.x;
        if (e < E) {
            int d = dst[e];
            int s = src[e];
            cv[row_start[d] + rank[e]] = make_int2(s, __float_as_int(dinv[s]));
        }
    }
}

template<int BN>
__global__ __launch_bounds__(256, 2) void k_gemm_bf(const unsigned short* __restrict__ Ahi,
                        const unsigned short* __restrict__ Alo,
                        const unsigned short* __restrict__ Whi, const unsigned short* __restrict__ Wlo,
                        _Float16* __restrict__ C, int N) {
    __shared__ unsigned short AhiS[4 * 64 * 8];
    __shared__ unsigned short AloS[4 * 64 * 8];
    gemm_body_bf<BN>(Ahi, Alo, Whi, Wlo, C, N, blockIdx.x, AhiS, AloS);
}

// ===================== aggregation =====================
// R15: WIDE gathers. One wave per node, but each gather instruction is 16B/lane:
//  - agg128: 16 lanes per edge row (256B), 4 edges per load instr (4x fewer issues than
//    R0's 4B/lane), header chunks of 16 edges (cv over-read 4x lower), headers distributed
//    via __shfl (bpermute), cross-group combine via shfl_xor(16/32).
//  - agg64: 8 lanes per edge row (128B), 8 edges per load instr (8x fewer than 2B/lane).
// Same bytes in flight per wave (4KB), strictly fewer instructions. If neutral, the
// ~4.8 TB/s random-gather ceiling is structural (bandwidth, not issue/latency).

__global__ __launch_bounds__(256) void k_agg128(const _Float16* __restrict__ t,
                      unsigned short* __restrict__ outHi, unsigned short* __restrict__ outLo,
                      const int* __restrict__ row_start, const int2* __restrict__ cv,
                      const float* __restrict__ dinv, const float* __restrict__ bias,
                      int N) {
    int gid = blockIdx.x * blockDim.x + threadIdx.x;
    int node = gid >> 6;
    int lane = gid & 63;
    if (node >= N) return;
    int l16 = lane & 15;
    int g4 = lane >> 4;
    int p = row_start[node];
    int end = row_start[node + 1];
    const f16x8v* tp8 = (const f16x8v*)t;   // row = 16 x f16x8
    float a[8];
    #pragma unroll
    for (int d = 0; d < 8; ++d) a[d] = 0.f;

    while (p < end) {
        int idx = p + l16;
        int2 h = (idx < end) ? cv[idx] : make_int2(0, 0);   // invalid: s=0, w=0
        #pragma unroll
        for (int jj = 0; jj < 4; ++jj) {
            int sl = jj * 4 + g4;                            // edge (p + sl) -> this group
            int s = __shfl(h.x, sl, 64);
            float w = __int_as_float(__shfl(h.y, sl, 64));
            f16x8v v = tp8[(size_t)s * 16 + l16];
            #pragma unroll
            for (int d = 0; d < 8; ++d) a[d] += w * (float)v[d];
        }
        p += 16;
    }
    #pragma unroll
    for (int d = 0; d < 8; ++d) {
        a[d] += __shfl_xor(a[d], 16, 64);
        a[d] += __shfl_xor(a[d], 32, 64);
    }
    float di = dinv[node];
    f16x8v sv = tp8[(size_t)node * 16 + l16];
    float4 b0 = ((const float4*)bias)[l16 * 2];
    float4 b1 = ((const float4*)bias)[l16 * 2 + 1];
    float bb[8] = {b0.x, b0.y, b0.z, b0.w, b1.x, b1.y, b1.z, b1.w};
    u16x8 hw, lw;
    #pragma unroll
    for (int d = 0; d < 8; ++d) {
        float r = fmaxf(di * a[d] + di * di * (float)sv[d] + bb[d], 0.f);
        unsigned short hx = f2bf_rne(r);
        hw[d] = hx;
        lw[d] = f2bf_rne(r - bf2f(hx));
    }
    if (g4 == 0) {
        *(u16x8*)&outHi[(size_t)node * 128 + l16 * 8] = hw;
        *(u16x8*)&outLo[(size_t)node * 128 + l16 * 8] = lw;
    }
}

// layer-3 aggregation (D=64) fused with final linear: out[i] = relu(agg_i + b) . Wf + bf
__global__ __launch_bounds__(256) void k_agg64_final(const _Float16* __restrict__ t, float* __restrict__ outp,
                      const int* __restrict__ row_start, const int2* __restrict__ cv,
                      const float* __restrict__ dinv, const float* __restrict__ bias,
                      const float* __restrict__ Wf, const float* __restrict__ bf,
                      int N) {
    int gid = blockIdx.x * blockDim.x + threadIdx.x;
    int node = gid >> 6;
    int lane = gid & 63;
    if (node >= N) return;
    int l8 = lane & 7;
    int g8 = lane >> 3;                    // 0..7
    int p = row_start[node];
    int end = row_start[node + 1];
    const f16x8v* tp8 = (const f16x8v*)t;  // row = 8 x f16x8
    float a[8];
    #pragma unroll
    for (int d = 0; d < 8; ++d) a[d] = 0.f;

    while (p < end) {
        int idx = p + (lane & 15);
        int2 h = (idx < end) ? cv[idx] : make_int2(0, 0);
        #pragma unroll
        for (int jj = 0; jj < 2; ++jj) {
            int sl = jj * 8 + g8;
            int s = __shfl(h.x, sl, 64);
            float w = __int_as_float(__shfl(h.y, sl, 64));
            f16x8v v = tp8[(size_t)s * 8 + l8];
            #pragma unroll
            for (int d = 0; d < 8; ++d) a[d] += w * (float)v[d];
        }
        p += 16;
    }
    #pragma unroll
    for (int d = 0; d < 8; ++d) {
        a[d] += __shfl_xor(a[d], 8, 64);
        a[d] += __shfl_xor(a[d], 16, 64);
        a[d] += __shfl_xor(a[d], 32, 64);
    }
    float di = dinv[node];
    f16x8v sv = tp8[(size_t)node * 8 + l8];
    float4 b0 = ((const float4*)bias)[l8 * 2];
    float4 b1 = ((const float4*)bias)[l8 * 2 + 1];
    float bb[8] = {b0.x, b0.y, b0.z, b0.w, b1.x, b1.y, b1.z, b1.w};
    float4 w0 = ((const float4*)Wf)[l8 * 2];
    float4 w1 = ((const float4*)Wf)[l8 * 2 + 1];
    float ww[8] = {w0.x, w0.y, w0.z, w0.w, w1.x, w1.y, w1.z, w1.w};
    float dot = 0.f;
    #pragma unroll
    for (int d = 0; d < 8; ++d) {
        float r = fmaxf(di * a[d] + di * di * (float)sv[d] + bb[d], 0.f);
        dot += r * ww[d];
    }
    dot += __shfl_xor(dot, 1, 64);
    dot += __shfl_xor(dot, 2, 64);
    dot += __shfl_xor(dot, 4, 64);
    if (lane == 0) outp[node] = dot + bf[0];
}

// ===================== launch =====================

extern "C" void kernel_launch(void* const* d_in, const int* in_sizes, int n_in,
                              void* d_out, int out_size, void* d_ws, size_t ws_size,
                              hipStream_t stream) {
    const float* x  = (const float*)d_in[0];
    const int*   src = (const int*)d_in[1];
    const int*   dst = (const int*)d_in[2];
    const float* W1 = (const float*)d_in[3];
    const float* b1 = (const float*)d_in[4];
    const float* W2 = (const float*)d_in[5];
    const float* b2 = (const float*)d_in[6];
    const float* W3 = (const float*)d_in[7];
    const float* b3 = (const float*)d_in[8];
    const float* Wf = (const float*)d_in[9];
    const float* bf = (const float*)d_in[10];
    float* out = (float*)d_out;

    const int N = 50000;
    const int E = 800000;

    char* ws = (char*)d_ws;
    size_t off = 0;
    auto alloc = [&](size_t bytes) -> void* {
        void* p = (void*)(ws + off);
        off += (bytes + 511) & ~((size_t)511);
        return p;
    };
    int*   deg       = (int*)alloc((size_t)N * 4);
    float* dinv      = (float*)alloc((size_t)N * 4);
    int*   row_start = (int*)alloc((size_t)(N + 1) * 4);
    int*   rank      = (int*)alloc((size_t)E * 4);
    int2*  cv        = (int2*)alloc((size_t)E * 8);
    _Float16* bufT   = (_Float16*)alloc((size_t)N * 128 * 2);        // GEMM out (gather source), fp16
    unsigned short* bufHi = (unsigned short*)alloc((size_t)N * 128 * 2);  // agg out hi-plane (GEMM A)
    unsigned short* bufLo = (unsigned short*)alloc((size_t)N * 128 * 2);  // agg out lo-plane (GEMM A)
    unsigned short* W1hi = (unsigned short*)alloc(128 * 128 * 2);
    unsigned short* W1lo = (unsigned short*)alloc(128 * 128 * 2);
    unsigned short* W2hi = (unsigned short*)alloc(128 * 128 * 2);
    unsigned short* W2lo = (unsigned short*)alloc(128 * 128 * 2);
    unsigned short* W3hi = (unsigned short*)alloc(128 * 64 * 2);
    unsigned short* W3lo = (unsigned short*)alloc(128 * 64 * 2);

    hipMemsetAsync(deg, 0, (size_t)N * 4, stream);

    k_count_wsplit<<<(E + 255) / 256, 256, 0, stream>>>(dst, deg, rank, W1, W2, W3,
                                                        W1hi, W1lo, W2hi, W2lo, W3hi, W3lo, E);
    int NB = (N + 1023) / 1024;   // 49 blocks
    k_scan<<<NB, 1024, 0, stream>>>(deg, dinv, row_start, N);

    int gemmGrid = (N + 63) / 64;          // 782
    int scatGrid = (E + 255) / 256;        // 3125
    int aggGrid = (N * 64 + 255) / 256;

    // fused: layer-1 GEMM + scatter (independent work overlapped, one node saved)
    k_gemm1_scatter<<<gemmGrid + scatGrid, 256, 0, stream>>>(x, W1hi, W1lo, bufT, N, gemmGrid,
                                                             src, dst, row_start, rank, dinv, cv, E);
    k_agg128<<<aggGrid, 256, 0, stream>>>(bufT, bufHi, bufLo, row_start, cv, dinv, b1, N);
    // layer 2
    k_gemm_bf<128><<<gemmGrid, 256, 0, stream>>>(bufHi, bufLo, W2hi, W2lo, bufT, N);
    k_agg128<<<aggGrid, 256, 0, stream>>>(bufT, bufHi, bufLo, row_start, cv, dinv, b2, N);
    // layer 3 (transform to 64 dims first, then aggregate + fused final linear)
    k_gemm_bf<64><<<gemmGrid, 256, 0, stream>>>(bufHi, bufLo, W3hi, W3lo, bufT, N);
    k_agg64_final<<<aggGrid, 256, 0, stream>>>(bufT, out, row_start, cv, dinv, b3, Wf, bf, N);
}